// Round 6
// baseline (135.553 us; speedup 1.0000x reference)
//
#include <hip/hip_runtime.h>
#include <stdint.h>

#define DD 128                 // drug feature dim
#define HH 32                  // hidden dim
#define TABQ (4096 * DD / 4)   // float4 count of drug table
#define BLOB_OFF (1u << 20)    // weight fragment blob offset inside d_ws (bytes)

typedef _Float16 f16;
typedef _Float16 f16x2 __attribute__((ext_vector_type(2)));
typedef _Float16 f16x4 __attribute__((ext_vector_type(4)));
typedef _Float16 f16x8 __attribute__((ext_vector_type(8)));
typedef float    f32x4 __attribute__((ext_vector_type(4)));
typedef uint32_t u32x4 __attribute__((ext_vector_type(4)));

// Pre-pass: (a) drug table f32->f16 (blocks 0..511); (b) weight-fragment blob
// at ws+1MB (block 512): W1 slots 0..511, W2 512..639, W3 640..767,
// W4-column-fragment 768..831 (lane m==0 holds W4[8q+j], else 0).
// Fragment contents are identical for A- and B-operand roles (16x16x32 A/B
// lane mappings are symmetric), so the swapped-MFMA main kernel reuses them.
__global__ __launch_bounds__(256)
void synergy_prepass(const float* __restrict__ drug,
                     const float* __restrict__ W1, const float* __restrict__ W2,
                     const float* __restrict__ W3, const float* __restrict__ W4,
                     f16* __restrict__ tab)
{
    const int tid = threadIdx.x;
    if ((int)blockIdx.x == 512) {
        f16x8* __restrict__ blob16 = (f16x8*)((char*)tab + BLOB_OFF);
        const float4* __restrict__ W1v = (const float4*)W1;
        #pragma unroll
        for (int p = 0; p < 2; ++p) {
            const int S = p * 256 + tid;
            const int t = S >> 8, f = (S >> 6) & 3, l = S & 63;
            const int mm = l & 15, qq = l >> 4;
            const int c4 = (t * 16 + mm) * (DD / 4) + f * 8 + qq * 2;
            const float4 w0 = W1v[c4], w1 = W1v[c4 + 1];
            f16x8 r;
            r[0]=(f16)w0.x; r[1]=(f16)w0.y; r[2]=(f16)w0.z; r[3]=(f16)w0.w;
            r[4]=(f16)w1.x; r[5]=(f16)w1.y; r[6]=(f16)w1.z; r[7]=(f16)w1.w;
            blob16[S] = r;
        }
        {
            const int B = tid & 127;
            const int t = B >> 6, l = B & 63;
            const int mm = l & 15, qq = l >> 4;
            const int c4 = (t * 16 + mm) * (HH / 4) + qq * 2;
            const float4* __restrict__ src = (tid < 128) ? (const float4*)W2 : (const float4*)W3;
            const float4 w0 = src[c4], w1 = src[c4 + 1];
            f16x8 r;
            r[0]=(f16)w0.x; r[1]=(f16)w0.y; r[2]=(f16)w0.z; r[3]=(f16)w0.w;
            r[4]=(f16)w1.x; r[5]=(f16)w1.y; r[6]=(f16)w1.z; r[7]=(f16)w1.w;
            blob16[512 + (tid & 128) + B] = r;
        }
        if (tid < 64) {                         // W4 column fragment
            const int mm = tid & 15, qq = tid >> 4;
            f16x8 r;
            #pragma unroll
            for (int j = 0; j < 8; ++j)
                r[j] = (mm == 0) ? (f16)W4[qq * 8 + j] : (f16)0.0f;
            blob16[768 + tid] = r;
        }
        return;
    }
    const int i = blockIdx.x * 256 + tid;
    if (i < TABQ) {
        const float4 v = ((const float4*)drug)[i];
        f16x4 h;
        h[0]=(f16)v.x; h[1]=(f16)v.y; h[2]=(f16)v.z; h[3]=(f16)v.w;
        ((f16x4*)tab)[i] = h;
    }
}

// pack two f32 -> one dword of 2 f16 (same RNE rounding as scalar casts)
static __device__ __forceinline__ uint32_t pkh(float a, float b) {
    f16x2 h; h[0] = (f16)a; h[1] = (f16)b;
    return __builtin_bit_cast(uint32_t, h);
}
static __device__ __forceinline__ void plswap32(uint32_t &a, uint32_t &b) {
#if __has_builtin(__builtin_amdgcn_permlane32_swap)
    auto r = __builtin_amdgcn_permlane32_swap(a, b, false, false);
    a = r[0]; b = r[1];
#else
    asm volatile("v_permlane32_swap_b32 %0, %1" : "+v"(a), "+v"(b));
#endif
}
static __device__ __forceinline__ void plswap16(uint32_t &a, uint32_t &b) {
#if __has_builtin(__builtin_amdgcn_permlane16_swap)
    auto r = __builtin_amdgcn_permlane16_swap(a, b, false, false);
    a = r[0]; b = r[1];
#else
    asm volatile("v_permlane16_swap_b32 %0, %1" : "+v"(a), "+v"(b));
#endif
}

// Pin a 4-VGPR fragment: the empty volatile asm makes the value an opaque
// register def -- the allocator can neither rematerialize it nor sink the
// originating load back into the loop (v6's failure mode: VGPR_Count=64
// proved the 13 "loop-invariant" weight loads were re-issued per iteration).
static __device__ __forceinline__ void pin4(f16x8 &w) {
    u32x4 t = __builtin_bit_cast(u32x4, w);
    asm volatile("" : "+v"(t));
    w = __builtin_bit_cast(f16x8, t);
}

// Inter-layer transition, all in-register. Input: swapped-MFMA output, lane
// (m,q): a0[r]=h[m][4q+r], a1[r]=h[m][16+4q+r]. Output: next-layer
// B-fragment, lane (m,q) holds h[m][8q..8q+7] after relu. (Verified v5.)
static __device__ __forceinline__ f16x8 transition(f32x4 a0, f32x4 a1) {
    uint32_t u0 = pkh(fmaxf(a0[0], 0.f), fmaxf(a0[1], 0.f));
    uint32_t u1 = pkh(fmaxf(a0[2], 0.f), fmaxf(a0[3], 0.f));
    uint32_t v0 = pkh(fmaxf(a1[0], 0.f), fmaxf(a1[1], 0.f));
    uint32_t v1 = pkh(fmaxf(a1[2], 0.f), fmaxf(a1[3], 0.f));
    plswap32(u0, v0);
    plswap32(u1, v1);
    plswap16(u0, v0);
    plswap16(u1, v1);
    u32x4 d; d[0] = u0; d[1] = u1; d[2] = v0; d[3] = v1;
    return __builtin_bit_cast(f16x8, d);
}

// Main v7: v6 + pinned weight registers. Cross-version evidence: v1
// (weights provably resident, VGPR=68) ran 9.7k cyc/wave-iter; v5 (weights
// re-read from LDS each iter) and v6 (compiler sank the weight loads back
// into the loop, VGPR=64) both ran ~12.4k. The per-phase operand re-fetch
// is the chain dominator. pin4() forbids the sink; budget 52 weights + 48
// gather + ~35 misc ~= 135 < 168 cap at __launch_bounds__(256,3).
// Spill tripwire: WRITE_SIZE must stay 3.9 MB.
__global__ __launch_bounds__(256, 3)
void synergy_main(const f16* __restrict__ tab, const int* __restrict__ edges,
                  const float* __restrict__ b1, const float* __restrict__ b2,
                  const float* __restrict__ b3, const float* __restrict__ b4,
                  float* __restrict__ out, int E, int NG)
{
    __shared__ __align__(16) float blds[96];    // b1|b2|b3 (32 floats each)

    const int tid  = threadIdx.x;
    const int wave = tid >> 6;
    const int lane = tid & 63;
    const int m    = lane & 15;
    const int q    = lane >> 4;

    const char* __restrict__ tabB   = (const char*)tab;
    const f16x8* __restrict__ blobG = (const f16x8*)(tabB + BLOB_OFF);

    if (tid < 96) {
        const float* __restrict__ src = (tid < 32) ? b1 : ((tid < 64) ? b2 : b3);
        blds[tid] = src[tid & 31];
    }
    __syncthreads();

    const int WSTR = (int)gridDim.x * 4;
    int g = (int)blockIdx.x * 4 + wave;
    if (g >= NG) return;

    // ---- weights in registers (loaded once, then PINNED against remat)
    f16x8 w1a[4], w1b[4];
    #pragma unroll
    for (int f = 0; f < 4; ++f) {
        w1a[f] = blobG[f * 64 + lane];
        w1b[f] = blobG[256 + f * 64 + lane];
    }
    f16x8 w2a = blobG[512 + lane], w2b = blobG[576 + lane];
    f16x8 w3a = blobG[640 + lane], w3b = blobG[704 + lane];
    f16x8 wf4 = blobG[768 + lane];
    #pragma unroll
    for (int f = 0; f < 4; ++f) { pin4(w1a[f]); pin4(w1b[f]); }
    pin4(w2a); pin4(w2b); pin4(w3a); pin4(w3b); pin4(wf4);
    const float b4v = b4[0];

    const int4* __restrict__ edges4 = (const int4*)edges;

    auto load_ed = [&](int gg) -> int4 {
        int e = (gg << 4) + m;
        e = (e < E) ? e : (E - 1);
        return edges4[e];
    };

    // Gather registers: v[f][t] holds edge-m's halfs [32f+8q, +8) of table t.
    f16x8 v[4][3];
    auto issue_gather = [&](const int4 ed) {
        const char* __restrict__ p0 = tabB + ((ed.x << 8) | (q << 4));
        const char* __restrict__ p1 = tabB + ((ed.y << 8) | (q << 4));
        const char* __restrict__ p2 = tabB + ((ed.z << 8) | (q << 4));
        #pragma unroll
        for (int f = 0; f < 4; ++f) {
            v[f][0] = *(const f16x8*)(p0 + f * 64);
            v[f][1] = *(const f16x8*)(p1 + f * 64);
            v[f][2] = *(const f16x8*)(p2 + f * 64);
        }
    };

    // ---- prologue: gathers for group g in flight
    int4 ed_cur = load_ed(g);
    issue_gather(ed_cur);
    int gn = g + WSTR;
    int4 ed_nxt = load_ed((gn < NG) ? gn : g);

    int wzero = 0;                       // opaque 0: pins BIAS reads in LDS
    for (;;) {
        asm volatile("" : "+v"(wzero)); // redefined every iter -> no LICM hoist
        const f32x4* __restrict__ bl = (const f32x4*)blds + wzero;

        // ---- Phase A: L1 (8 MFMAs, K=128, swapped: D = W1.h^T)
        f32x4 acc0 = bl[q];             // b1[4q..4q+3]
        f32x4 acc1 = bl[4 + q];         // b1[16+4q..]
        #pragma unroll
        for (int f = 0; f < 4; ++f) {
            const f16x8 p = v[f][0] * v[f][1] * v[f][2];
            acc0 = __builtin_amdgcn_mfma_f32_16x16x32_f16(w1a[f], p, acc0, 0, 0, 0);
            acc1 = __builtin_amdgcn_mfma_f32_16x16x32_f16(w1b[f], p, acc1, 0, 0, 0);
        }
        const f16x8 h1 = transition(acc0, acc1);

        // ---- refill: issue next group's 12 gathers NOW; flight covered by B-D
        const bool last = (gn >= NG);
        int4 ed_fut = ed_nxt;
        if (!last) {
            issue_gather(ed_nxt);
            const int gf = gn + WSTR;
            ed_fut = load_ed((gf < NG) ? gf : g);
        }

        // ---- Phase B: L2
        f32x4 c0 = bl[8 + q];
        f32x4 c1 = bl[12 + q];
        c0 = __builtin_amdgcn_mfma_f32_16x16x32_f16(w2a, h1, c0, 0, 0, 0);
        c1 = __builtin_amdgcn_mfma_f32_16x16x32_f16(w2b, h1, c1, 0, 0, 0);
        const f16x8 h2 = transition(c0, c1);

        // ---- Phase C: L3
        f32x4 d0 = bl[16 + q];
        f32x4 d1 = bl[20 + q];
        d0 = __builtin_amdgcn_mfma_f32_16x16x32_f16(w3a, h2, d0, 0, 0, 0);
        d1 = __builtin_amdgcn_mfma_f32_16x16x32_f16(w3b, h2, d1, 0, 0, 0);
        const f16x8 h3 = transition(d0, d1);

        // ---- Phase D: L4 vs zero-padded W4 row; lanes q==0 hold z[m] in reg0
        {
            f32x4 z = {b4v, b4v, b4v, b4v};
            z = __builtin_amdgcn_mfma_f32_16x16x32_f16(wf4, h3, z, 0, 0, 0);
            if (q == 0) {
                const int e0 = (g << 4) + m;
                if (e0 < E) out[e0] = 1.0f / (1.0f + __expf(-z[0]));
            }
        }
        // label pass-through
        const int eL = (g << 4) + lane;
        if (lane < 16 && eL < E) out[E + eL] = (float)ed_cur.w;

        if (last) break;
        g = gn; gn += WSTR; ed_cur = ed_nxt; ed_nxt = ed_fut;
    }
}

extern "C" void kernel_launch(void* const* d_in, const int* in_sizes, int n_in,
                              void* d_out, int out_size, void* d_ws, size_t ws_size,
                              hipStream_t stream)
{
    const float* drug  = (const float*)d_in[0];
    // d_in[1] (cell_hidden_out), d_in[3] (proj_W), d_in[4] (proj_b): dead code
    const int*   edges = (const int*)d_in[2];
    const float* W1 = (const float*)d_in[5];
    const float* b1 = (const float*)d_in[6];
    const float* W2 = (const float*)d_in[7];
    const float* b2 = (const float*)d_in[8];
    const float* W3 = (const float*)d_in[9];
    const float* b3 = (const float*)d_in[10];
    const float* W4 = (const float*)d_in[11];
    const float* b4 = (const float*)d_in[12];
    float* out = (float*)d_out;
    f16*   tab = (f16*)d_ws;   // [0,1MB): f16 table; [1MB,+13KB): weight blob

    const int E  = in_sizes[2] / 4;
    const int NG = (E + 15) / 16;

    hipLaunchKernelGGL(synergy_prepass, dim3(513), dim3(256), 0, stream,
                       drug, W1, W2, W3, W4, tab);
    int blocks = (NG + 3) / 4;
    if (blocks > 768) blocks = 768;          // 3 blocks/CU x 256 CUs
    hipLaunchKernelGGL(synergy_main, dim3(blocks), dim3(256), 0, stream,
                       tab, edges, b1, b2, b3, b4, out, E, NG);
}

// Round 7
// 114.559 us; speedup vs baseline: 1.1833x; 1.1833x over previous
//
#include <hip/hip_runtime.h>
#include <stdint.h>

#define DD 128                 // drug feature dim
#define HH 32                  // hidden dim
#define TABQ (4096 * DD / 4)   // float4 count of drug table
#define BLOB_OFF (1u << 20)    // weight fragment blob offset inside d_ws (bytes)

typedef _Float16 f16;
typedef _Float16 f16x2 __attribute__((ext_vector_type(2)));
typedef _Float16 f16x4 __attribute__((ext_vector_type(4)));
typedef _Float16 f16x8 __attribute__((ext_vector_type(8)));
typedef float    f32x4 __attribute__((ext_vector_type(4)));
typedef uint32_t u32x4 __attribute__((ext_vector_type(4)));

#define GL1(p)  ((const __attribute__((address_space(1))) void*)(p))
#define LDS3(p) ((__attribute__((address_space(3))) void*)(p))

// Pre-pass: (a) drug table f32->f16 (blocks 0..511); (b) weight-fragment blob
// at ws+1MB (block 512): W1 slots 0..511, W2 512..639, W3 640..767,
// W4-column-fragment 768..831. Fragments are role-symmetric (A vs B operand),
// so the swapped-MFMA main kernel reuses them unchanged.
__global__ __launch_bounds__(256)
void synergy_prepass(const float* __restrict__ drug,
                     const float* __restrict__ W1, const float* __restrict__ W2,
                     const float* __restrict__ W3, const float* __restrict__ W4,
                     f16* __restrict__ tab)
{
    const int tid = threadIdx.x;
    if ((int)blockIdx.x == 512) {
        f16x8* __restrict__ blob16 = (f16x8*)((char*)tab + BLOB_OFF);
        const float4* __restrict__ W1v = (const float4*)W1;
        #pragma unroll
        for (int p = 0; p < 2; ++p) {
            const int S = p * 256 + tid;
            const int t = S >> 8, f = (S >> 6) & 3, l = S & 63;
            const int mm = l & 15, qq = l >> 4;
            const int c4 = (t * 16 + mm) * (DD / 4) + f * 8 + qq * 2;
            const float4 w0 = W1v[c4], w1 = W1v[c4 + 1];
            f16x8 r;
            r[0]=(f16)w0.x; r[1]=(f16)w0.y; r[2]=(f16)w0.z; r[3]=(f16)w0.w;
            r[4]=(f16)w1.x; r[5]=(f16)w1.y; r[6]=(f16)w1.z; r[7]=(f16)w1.w;
            blob16[S] = r;
        }
        {
            const int B = tid & 127;
            const int t = B >> 6, l = B & 63;
            const int mm = l & 15, qq = l >> 4;
            const int c4 = (t * 16 + mm) * (HH / 4) + qq * 2;
            const float4* __restrict__ src = (tid < 128) ? (const float4*)W2 : (const float4*)W3;
            const float4 w0 = src[c4], w1 = src[c4 + 1];
            f16x8 r;
            r[0]=(f16)w0.x; r[1]=(f16)w0.y; r[2]=(f16)w0.z; r[3]=(f16)w0.w;
            r[4]=(f16)w1.x; r[5]=(f16)w1.y; r[6]=(f16)w1.z; r[7]=(f16)w1.w;
            blob16[512 + (tid & 128) + B] = r;
        }
        if (tid < 64) {                         // W4 column fragment
            const int mm = tid & 15, qq = tid >> 4;
            f16x8 r;
            #pragma unroll
            for (int j = 0; j < 8; ++j)
                r[j] = (mm == 0) ? (f16)W4[qq * 8 + j] : (f16)0.0f;
            blob16[768 + tid] = r;
        }
        return;
    }
    const int i = blockIdx.x * 256 + tid;
    if (i < TABQ) {
        const float4 v = ((const float4*)drug)[i];
        f16x4 h;
        h[0]=(f16)v.x; h[1]=(f16)v.y; h[2]=(f16)v.z; h[3]=(f16)v.w;
        ((f16x4*)tab)[i] = h;
    }
}

// pack two f32 -> one dword of 2 f16 (same RNE rounding as scalar casts)
static __device__ __forceinline__ uint32_t pkh(float a, float b) {
    f16x2 h; h[0] = (f16)a; h[1] = (f16)b;
    return __builtin_bit_cast(uint32_t, h);
}
static __device__ __forceinline__ void plswap32(uint32_t &a, uint32_t &b) {
#if __has_builtin(__builtin_amdgcn_permlane32_swap)
    auto r = __builtin_amdgcn_permlane32_swap(a, b, false, false);
    a = r[0]; b = r[1];
#else
    asm volatile("v_permlane32_swap_b32 %0, %1" : "+v"(a), "+v"(b));
#endif
}
static __device__ __forceinline__ void plswap16(uint32_t &a, uint32_t &b) {
#if __has_builtin(__builtin_amdgcn_permlane16_swap)
    auto r = __builtin_amdgcn_permlane16_swap(a, b, false, false);
    a = r[0]; b = r[1];
#else
    asm volatile("v_permlane16_swap_b32 %0, %1" : "+v"(a), "+v"(b));
#endif
}

// Pin a 4-VGPR fragment against load-sinking/remat (v6 lesson).
static __device__ __forceinline__ void pin4(f16x8 &w) {
    u32x4 t = __builtin_bit_cast(u32x4, w);
    asm volatile("" : "+v"(t));
    w = __builtin_bit_cast(f16x8, t);
}

// Inter-layer transition, all in-register (verified in v5). Input: swapped
// MFMA output, lane (m,q): a0[r]=h[m][4q+r], a1[r]=h[m][16+4q+r]. Output:
// next layer's B-fragment, lane (m,q) holds relu(h)[m][8q..8q+7].
static __device__ __forceinline__ f16x8 transition(f32x4 a0, f32x4 a1) {
    uint32_t u0 = pkh(fmaxf(a0[0], 0.f), fmaxf(a0[1], 0.f));
    uint32_t u1 = pkh(fmaxf(a0[2], 0.f), fmaxf(a0[3], 0.f));
    uint32_t v0 = pkh(fmaxf(a1[0], 0.f), fmaxf(a1[1], 0.f));
    uint32_t v1 = pkh(fmaxf(a1[2], 0.f), fmaxf(a1[3], 0.f));
    plswap32(u0, v0);
    plswap32(u1, v1);
    plswap16(u0, v0);
    plswap16(u1, v1);
    u32x4 d; d[0] = u0; d[1] = u1; d[2] = v0; d[3] = v1;
    return __builtin_bit_cast(f16x8, d);
}

// Main v8: v1's MEMORY engine + v5/v7's COMPUTE engine.
// Evidence: v3/v5/v7 (per-lane register gathers: 16 uncoalesceable 64B
// requests/instr) all plateau at 12-21k cyc/iter regardless of weight
// placement or occupancy -- per-CU memory REQUEST throughput is the wall.
// v1's rotation-swizzled global_load_lds reads 4 contiguous 256B rows per
// instruction (~4 merged requests, 4x fewer) and ran 9.7k cyc/iter even
// while paying for hbuf round-trips. So: stage via DMA (v1 verbatim:
// tail-issue, loop-top vmcnt(0)+sched_barrier as the sole drain), compute
// via swapped-MFMA + permlane transitions (v5 verbatim: no hbuf), weights
// pinned in regs (v7), biases in LDS behind the wzero pin.
__global__ __launch_bounds__(256, 3)
void synergy_main(const f16* __restrict__ tab, const int* __restrict__ edges,
                  const float* __restrict__ b1, const float* __restrict__ b2,
                  const float* __restrict__ b3, const float* __restrict__ b4,
                  float* __restrict__ out, int E, int NG)
{
    __shared__ __align__(16) f16 stage[4][6144];   // 48 KiB: 48 rows x 256 B per wave
    __shared__ __align__(16) float blds[96];       // b1|b2|b3 (32 floats each)

    const int tid  = threadIdx.x;
    const int wave = tid >> 6;
    const int lane = tid & 63;
    const int m    = lane & 15;
    const int q    = lane >> 4;

    const char* __restrict__ tabB   = (const char*)tab;
    const f16x8* __restrict__ blobG = (const f16x8*)(tabB + BLOB_OFF);

    if (tid < 96) {
        const float* __restrict__ src = (tid < 32) ? b1 : ((tid < 64) ? b2 : b3);
        blds[tid] = src[tid & 31];
    }
    __syncthreads();

    const int WSTR = (int)gridDim.x * 4;
    int g = (int)blockIdx.x * 4 + wave;
    if (g >= NG) return;

    // ---- weights in registers (loaded once, pinned against sinking)
    f16x8 w1a[4], w1b[4];
    #pragma unroll
    for (int f = 0; f < 4; ++f) {
        w1a[f] = blobG[f * 64 + lane];
        w1b[f] = blobG[256 + f * 64 + lane];
    }
    f16x8 w2a = blobG[512 + lane], w2b = blobG[576 + lane];
    f16x8 w3a = blobG[640 + lane], w3b = blobG[704 + lane];
    f16x8 wf4 = blobG[768 + lane];
    #pragma unroll
    for (int f = 0; f < 4; ++f) { pin4(w1a[f]); pin4(w1b[f]); }
    pin4(w2a); pin4(w2b); pin4(w3a); pin4(w3b); pin4(wf4);
    const float b4v = b4[0];

    f16* __restrict__ stg = stage[wave];
    const int4* __restrict__ edges4 = (const int4*)edges;

    auto load_ed = [&](int gg) -> int4 {
        int e = (gg << 4) + m;
        e = (e < E) ? e : (E - 1);
        return edges4[e];
    };
    // Rotation-swizzled gather: DMA (t,gg) -> lane 16q+m stages row 4gg+q,
    // slot m, fetching global segment (m + 4gg + q) & 15 of that row.
    // Each instruction reads 4 CONTIGUOUS 256B rows -> coalescer-merged.
    auto issue_dma = [&](const int4 ed) {
        int rowb[12];
        #pragma unroll
        for (int gg = 0; gg < 4; ++gg) {
            const int src = 4 * gg + q;
            rowb[0 * 4 + gg] = __shfl(ed.x, src, 64) << 8;
            rowb[1 * 4 + gg] = __shfl(ed.y, src, 64) << 8;
            rowb[2 * 4 + gg] = __shfl(ed.z, src, 64) << 8;
        }
        __builtin_amdgcn_sched_barrier(0);
        #pragma unroll
        for (int t = 0; t < 3; ++t)
            #pragma unroll
            for (int gg = 0; gg < 4; ++gg) {
                const int seg16 = ((m + 4 * gg + q) & 15) << 4;
                __builtin_amdgcn_global_load_lds(
                    GL1(tabB + (size_t)(rowb[t * 4 + gg] + seg16)),
                    LDS3((char*)stg + (t * 16 + 4 * gg) * 256), 16, 0, 0);
            }
    };

    // ---- prologue
    int4 ed_cur = load_ed(g);
    issue_dma(ed_cur);
    int gn = g + WSTR;
    int4 ed_nxt = load_ed((gn < NG) ? gn : g);

    int wzero = 0;                       // opaque 0: pins bias reads in LDS
    for (;;) {
        __builtin_amdgcn_s_waitcnt(0x0F70);     // vmcnt(0): stage DMAs landed
        __builtin_amdgcn_sched_barrier(0);
        asm volatile("" : "+v"(wzero)); // redefined every iter -> no LICM hoist
        const f32x4* __restrict__ bl = (const f32x4*)blds + wzero;

        // ---- Phase A: L1 (8 MFMAs, K=128, swapped: D = W1.h^T); reads stage
        f32x4 acc0 = bl[q];             // b1[4q..4q+3]
        f32x4 acc1 = bl[4 + q];         // b1[16+4q..]
        #pragma unroll
        for (int f = 0; f < 4; ++f) {
            const int slot = (((f * 4 + q) - m) & 15) << 3;
            const f16x8 v0 = *(const f16x8*)(stg + (0 * 16 + m) * 128 + slot);
            const f16x8 v1 = *(const f16x8*)(stg + (1 * 16 + m) * 128 + slot);
            const f16x8 v2 = *(const f16x8*)(stg + (2 * 16 + m) * 128 + slot);
            const f16x8 p = v0 * v1 * v2;
            acc0 = __builtin_amdgcn_mfma_f32_16x16x32_f16(w1a[f], p, acc0, 0, 0, 0);
            acc1 = __builtin_amdgcn_mfma_f32_16x16x32_f16(w1b[f], p, acc1, 0, 0, 0);
        }
        const f16x8 h1 = transition(acc0, acc1);

        // ---- prefetch edges two groups ahead (register; drained next top-wait)
        const int gf = gn + WSTR;
        const int4 ed_fut = load_ed((gf < NG) ? gf : g);

        // ---- Phase B: L2
        f32x4 c0 = bl[8 + q];
        f32x4 c1 = bl[12 + q];
        c0 = __builtin_amdgcn_mfma_f32_16x16x32_f16(w2a, h1, c0, 0, 0, 0);
        c1 = __builtin_amdgcn_mfma_f32_16x16x32_f16(w2b, h1, c1, 0, 0, 0);
        const f16x8 h2 = transition(c0, c1);

        // ---- Phase C: L3
        f32x4 d0 = bl[16 + q];
        f32x4 d1 = bl[20 + q];
        d0 = __builtin_amdgcn_mfma_f32_16x16x32_f16(w3a, h2, d0, 0, 0, 0);
        d1 = __builtin_amdgcn_mfma_f32_16x16x32_f16(w3b, h2, d1, 0, 0, 0);
        const f16x8 h3 = transition(d0, d1);

        // ---- Phase D: L4 vs zero-padded W4 column; lanes q==0 hold z[m]
        {
            f32x4 z = {b4v, b4v, b4v, b4v};
            z = __builtin_amdgcn_mfma_f32_16x16x32_f16(wf4, h3, z, 0, 0, 0);
            if (q == 0) {
                const int e0 = (g << 4) + m;
                if (e0 < E) out[e0] = 1.0f / (1.0f + __expf(-z[0]));
            }
        }
        // label pass-through
        const int eL = (g << 4) + lane;
        if (lane < 16 && eL < E) out[E + eL] = (float)ed_cur.w;

        // ---- TAIL: issue next group's DMAs (nothing after this reads LDS)
        if (gn >= NG) break;
        issue_dma(ed_nxt);
        g = gn; gn = gf; ed_cur = ed_nxt; ed_nxt = ed_fut;
    }
}

extern "C" void kernel_launch(void* const* d_in, const int* in_sizes, int n_in,
                              void* d_out, int out_size, void* d_ws, size_t ws_size,
                              hipStream_t stream)
{
    const float* drug  = (const float*)d_in[0];
    // d_in[1] (cell_hidden_out), d_in[3] (proj_W), d_in[4] (proj_b): dead code
    const int*   edges = (const int*)d_in[2];
    const float* W1 = (const float*)d_in[5];
    const float* b1 = (const float*)d_in[6];
    const float* W2 = (const float*)d_in[7];
    const float* b2 = (const float*)d_in[8];
    const float* W3 = (const float*)d_in[9];
    const float* b3 = (const float*)d_in[10];
    const float* W4 = (const float*)d_in[11];
    const float* b4 = (const float*)d_in[12];
    float* out = (float*)d_out;
    f16*   tab = (f16*)d_ws;   // [0,1MB): f16 table; [1MB,+13KB): weight blob

    const int E  = in_sizes[2] / 4;
    const int NG = (E + 15) / 16;

    hipLaunchKernelGGL(synergy_prepass, dim3(513), dim3(256), 0, stream,
                       drug, W1, W2, W3, W4, tab);
    int blocks = (NG + 3) / 4;
    if (blocks > 768) blocks = 768;          // 3 blocks/CU x 256 CUs
    hipLaunchKernelGGL(synergy_main, dim3(blocks), dim3(256), 0, stream,
                       tab, edges, b1, b2, b3, b4, out, E, NG);
}

// Round 8
// 111.754 us; speedup vs baseline: 1.2130x; 1.0251x over previous
//
#include <hip/hip_runtime.h>
#include <stdint.h>

#define DD 128                 // drug feature dim
#define HH 32                  // hidden dim
#define TABQ (4096 * DD / 4)   // float4 count of drug table
#define BLOB_OFF (1u << 20)    // weight fragment blob offset inside d_ws (bytes)

typedef _Float16 f16;
typedef _Float16 f16x2 __attribute__((ext_vector_type(2)));
typedef _Float16 f16x4 __attribute__((ext_vector_type(4)));
typedef _Float16 f16x8 __attribute__((ext_vector_type(8)));
typedef float    f32x4 __attribute__((ext_vector_type(4)));
typedef uint32_t u32x4 __attribute__((ext_vector_type(4)));

#define GL1(p)  ((const __attribute__((address_space(1))) void*)(p))
#define LDS3(p) ((__attribute__((address_space(3))) void*)(p))

// Pre-pass: (a) drug table f32->f16 (blocks 0..511); (b) weight-fragment blob
// at ws+1MB (block 512): W1 slots 0..511, W2 512..639, W3 640..767,
// W4-column-fragment 768..831. Fragments are role-symmetric (A vs B operand),
// so the swapped-MFMA main kernel reuses them unchanged.
__global__ __launch_bounds__(256)
void synergy_prepass(const float* __restrict__ drug,
                     const float* __restrict__ W1, const float* __restrict__ W2,
                     const float* __restrict__ W3, const float* __restrict__ W4,
                     f16* __restrict__ tab)
{
    const int tid = threadIdx.x;
    if ((int)blockIdx.x == 512) {
        f16x8* __restrict__ blob16 = (f16x8*)((char*)tab + BLOB_OFF);
        const float4* __restrict__ W1v = (const float4*)W1;
        #pragma unroll
        for (int p = 0; p < 2; ++p) {
            const int S = p * 256 + tid;
            const int t = S >> 8, f = (S >> 6) & 3, l = S & 63;
            const int mm = l & 15, qq = l >> 4;
            const int c4 = (t * 16 + mm) * (DD / 4) + f * 8 + qq * 2;
            const float4 w0 = W1v[c4], w1 = W1v[c4 + 1];
            f16x8 r;
            r[0]=(f16)w0.x; r[1]=(f16)w0.y; r[2]=(f16)w0.z; r[3]=(f16)w0.w;
            r[4]=(f16)w1.x; r[5]=(f16)w1.y; r[6]=(f16)w1.z; r[7]=(f16)w1.w;
            blob16[S] = r;
        }
        {
            const int B = tid & 127;
            const int t = B >> 6, l = B & 63;
            const int mm = l & 15, qq = l >> 4;
            const int c4 = (t * 16 + mm) * (HH / 4) + qq * 2;
            const float4* __restrict__ src = (tid < 128) ? (const float4*)W2 : (const float4*)W3;
            const float4 w0 = src[c4], w1 = src[c4 + 1];
            f16x8 r;
            r[0]=(f16)w0.x; r[1]=(f16)w0.y; r[2]=(f16)w0.z; r[3]=(f16)w0.w;
            r[4]=(f16)w1.x; r[5]=(f16)w1.y; r[6]=(f16)w1.z; r[7]=(f16)w1.w;
            blob16[512 + (tid & 128) + B] = r;
        }
        if (tid < 64) {                         // W4 column fragment
            const int mm = tid & 15, qq = tid >> 4;
            f16x8 r;
            #pragma unroll
            for (int j = 0; j < 8; ++j)
                r[j] = (mm == 0) ? (f16)W4[qq * 8 + j] : (f16)0.0f;
            blob16[768 + tid] = r;
        }
        return;
    }
    const int i = blockIdx.x * 256 + tid;
    if (i < TABQ) {
        const float4 v = ((const float4*)drug)[i];
        f16x4 h;
        h[0]=(f16)v.x; h[1]=(f16)v.y; h[2]=(f16)v.z; h[3]=(f16)v.w;
        ((f16x4*)tab)[i] = h;
    }
}

// pack two f32 -> one dword of 2 f16 (same RNE rounding as scalar casts)
static __device__ __forceinline__ uint32_t pkh(float a, float b) {
    f16x2 h; h[0] = (f16)a; h[1] = (f16)b;
    return __builtin_bit_cast(uint32_t, h);
}
static __device__ __forceinline__ void plswap32(uint32_t &a, uint32_t &b) {
#if __has_builtin(__builtin_amdgcn_permlane32_swap)
    auto r = __builtin_amdgcn_permlane32_swap(a, b, false, false);
    a = r[0]; b = r[1];
#else
    asm volatile("v_permlane32_swap_b32 %0, %1" : "+v"(a), "+v"(b));
#endif
}
static __device__ __forceinline__ void plswap16(uint32_t &a, uint32_t &b) {
#if __has_builtin(__builtin_amdgcn_permlane16_swap)
    auto r = __builtin_amdgcn_permlane16_swap(a, b, false, false);
    a = r[0]; b = r[1];
#else
    asm volatile("v_permlane16_swap_b32 %0, %1" : "+v"(a), "+v"(b));
#endif
}

// Pin a 4-VGPR value against load-sinking/remat (v6 lesson: without this the
// allocator re-issues "loop-invariant" loads inside the loop).
static __device__ __forceinline__ void pin4(f16x8 &w) {
    u32x4 t = __builtin_bit_cast(u32x4, w);
    asm volatile("" : "+v"(t));
    w = __builtin_bit_cast(f16x8, t);
}
static __device__ __forceinline__ void pin4f(f32x4 &w) {
    asm volatile("" : "+v"(w));
}

// Inter-layer transition, all in-register (verified in v5). Input: swapped
// MFMA output, lane (m,q): a0[r]=h[m][4q+r], a1[r]=h[m][16+4q+r]. Output:
// next layer's B-fragment, lane (m,q) holds relu(h)[m][8q..8q+7].
static __device__ __forceinline__ f16x8 transition(f32x4 a0, f32x4 a1) {
    uint32_t u0 = pkh(fmaxf(a0[0], 0.f), fmaxf(a0[1], 0.f));
    uint32_t u1 = pkh(fmaxf(a0[2], 0.f), fmaxf(a0[3], 0.f));
    uint32_t v0 = pkh(fmaxf(a1[0], 0.f), fmaxf(a1[1], 0.f));
    uint32_t v1 = pkh(fmaxf(a1[2], 0.f), fmaxf(a1[3], 0.f));
    plswap32(u0, v0);
    plswap32(u1, v1);
    plswap16(u0, v0);
    plswap16(u1, v1);
    u32x4 d; d[0] = u0; d[1] = u1; d[2] = v0; d[3] = v1;
    return __builtin_bit_cast(f16x8, d);
}

// Main v9: v8 + async-STAGE overlap (T14) + counted vmcnt (T4).
// v8's loop-top vmcnt(0) exposed the full DMA flight (tail-issue = zero
// same-wave coverage) AND drained phase D's stores. Now: DMAs for group n+1
// are issued right after transition(h1) -- phase A's stage reads are retired
// by then (the MFMAs consumed them) -- so phases B-D cover the L2 flight.
// Loop-top waits vmcnt(3): per iteration, exactly 3 VMEM ops are younger
// than the last DMA (ed prefetch load + result store + label store), and
// vmcnt retires in order, so vmcnt(3) == "all 12 DMAs landed" without
// waiting for store-acks. sched_barrier(0) fences pin the VMEM program
// order. Prerequisite: NO LDS reads between issue and the top wait, so
// biases are pinned per-lane registers (each lane only needs b[4q+r]);
// blds/wzero/__syncthreads deleted -- waves are fully independent.
__global__ __launch_bounds__(256, 3)
void synergy_main(const f16* __restrict__ tab, const int* __restrict__ edges,
                  const float* __restrict__ b1, const float* __restrict__ b2,
                  const float* __restrict__ b3, const float* __restrict__ b4,
                  float* __restrict__ out, int E, int NG)
{
    __shared__ __align__(16) f16 stage[4][6144];   // 48 KiB: 48 rows x 256 B per wave

    const int tid  = threadIdx.x;
    const int wave = tid >> 6;
    const int lane = tid & 63;
    const int m    = lane & 15;
    const int q    = lane >> 4;

    const char* __restrict__ tabB   = (const char*)tab;
    const f16x8* __restrict__ blobG = (const f16x8*)(tabB + BLOB_OFF);

    const int WSTR = (int)gridDim.x * 4;
    int g = (int)blockIdx.x * 4 + wave;
    if (g >= NG) return;

    // ---- weights in registers (loaded once, pinned against sinking)
    f16x8 w1a[4], w1b[4];
    #pragma unroll
    for (int f = 0; f < 4; ++f) {
        w1a[f] = blobG[f * 64 + lane];
        w1b[f] = blobG[256 + f * 64 + lane];
    }
    f16x8 w2a = blobG[512 + lane], w2b = blobG[576 + lane];
    f16x8 w3a = blobG[640 + lane], w3b = blobG[704 + lane];
    f16x8 wf4 = blobG[768 + lane];
    #pragma unroll
    for (int f = 0; f < 4; ++f) { pin4(w1a[f]); pin4(w1b[f]); }
    pin4(w2a); pin4(w2b); pin4(w3a); pin4(w3b); pin4(wf4);

    // ---- biases in registers: lane (m,q) needs b[4q+r] and b[16+4q+r]
    f32x4 bb1a = *(const f32x4*)(b1 + 4 * q), bb1b = *(const f32x4*)(b1 + 16 + 4 * q);
    f32x4 bb2a = *(const f32x4*)(b2 + 4 * q), bb2b = *(const f32x4*)(b2 + 16 + 4 * q);
    f32x4 bb3a = *(const f32x4*)(b3 + 4 * q), bb3b = *(const f32x4*)(b3 + 16 + 4 * q);
    pin4f(bb1a); pin4f(bb1b); pin4f(bb2a); pin4f(bb2b); pin4f(bb3a); pin4f(bb3b);
    const float b4v = b4[0];

    f16* __restrict__ stg = stage[wave];
    const int4* __restrict__ edges4 = (const int4*)edges;

    auto load_ed = [&](int gg) -> int4 {
        int e = (gg << 4) + m;
        e = (e < E) ? e : (E - 1);
        return edges4[e];
    };
    // Rotation-swizzled gather: DMA (t,gg) -> lane 16q+m stages row 4gg+q,
    // slot m, fetching global segment (m + 4gg + q) & 15 of that row.
    // Each instruction reads 4 CONTIGUOUS 256B rows -> coalescer-merged.
    auto issue_dma = [&](const int4 ed) {
        int rowb[12];
        #pragma unroll
        for (int gg = 0; gg < 4; ++gg) {
            const int src = 4 * gg + q;
            rowb[0 * 4 + gg] = __shfl(ed.x, src, 64) << 8;
            rowb[1 * 4 + gg] = __shfl(ed.y, src, 64) << 8;
            rowb[2 * 4 + gg] = __shfl(ed.z, src, 64) << 8;
        }
        __builtin_amdgcn_sched_barrier(0);
        #pragma unroll
        for (int t = 0; t < 3; ++t)
            #pragma unroll
            for (int gg = 0; gg < 4; ++gg) {
                const int seg16 = ((m + 4 * gg + q) & 15) << 4;
                __builtin_amdgcn_global_load_lds(
                    GL1(tabB + (size_t)(rowb[t * 4 + gg] + seg16)),
                    LDS3((char*)stg + (t * 16 + 4 * gg) * 256), 16, 0, 0);
            }
        __builtin_amdgcn_sched_barrier(0);   // nothing crosses the DMA cluster
    };

    // ---- prologue: group g staged and fully drained once
    int4 ed_cur = load_ed(g);
    issue_dma(ed_cur);
    int gn = g + WSTR;
    int4 ed_nxt = load_ed((gn < NG) ? gn : g);
    __builtin_amdgcn_s_waitcnt(0x0F70);          // vmcnt(0): one-time drain
    __builtin_amdgcn_sched_barrier(0);

    for (;;) {
        // steady state: all 12 DMAs are older than exactly 3 VMEM ops
        __builtin_amdgcn_s_waitcnt(0x0F73);      // vmcnt(3): stage landed
        __builtin_amdgcn_sched_barrier(0);

        // ---- Phase A: L1 (8 MFMAs, K=128, swapped: D = W1.h^T); reads stage
        f32x4 acc0 = bb1a;
        f32x4 acc1 = bb1b;
        #pragma unroll
        for (int f = 0; f < 4; ++f) {
            const int slot = (((f * 4 + q) - m) & 15) << 3;
            const f16x8 v0 = *(const f16x8*)(stg + (0 * 16 + m) * 128 + slot);
            const f16x8 v1 = *(const f16x8*)(stg + (1 * 16 + m) * 128 + slot);
            const f16x8 v2 = *(const f16x8*)(stg + (2 * 16 + m) * 128 + slot);
            const f16x8 p = v0 * v1 * v2;
            acc0 = __builtin_amdgcn_mfma_f32_16x16x32_f16(w1a[f], p, acc0, 0, 0, 0);
            acc1 = __builtin_amdgcn_mfma_f32_16x16x32_f16(w1b[f], p, acc1, 0, 0, 0);
        }
        const f16x8 h1 = transition(acc0, acc1);
        // stage reads are retired (MFMAs consumed them) -> safe to overwrite

        // ---- async stage refill: flight covered by phases B-D (same wave)
        const bool last = (gn >= NG);
        const int gf = gn + WSTR;
        int4 ed_fut = ed_nxt;
        if (!last) {
            issue_dma(ed_nxt);                   // 12 DMAs
            ed_fut = load_ed((gf < NG) ? gf : g); // younger op #1
        }

        // ---- Phase B: L2 (pure register)
        f32x4 c0 = bb2a;
        f32x4 c1 = bb2b;
        c0 = __builtin_amdgcn_mfma_f32_16x16x32_f16(w2a, h1, c0, 0, 0, 0);
        c1 = __builtin_amdgcn_mfma_f32_16x16x32_f16(w2b, h1, c1, 0, 0, 0);
        const f16x8 h2 = transition(c0, c1);

        // ---- Phase C: L3 (pure register)
        f32x4 d0 = bb3a;
        f32x4 d1 = bb3b;
        d0 = __builtin_amdgcn_mfma_f32_16x16x32_f16(w3a, h2, d0, 0, 0, 0);
        d1 = __builtin_amdgcn_mfma_f32_16x16x32_f16(w3b, h2, d1, 0, 0, 0);
        const f16x8 h3 = transition(d0, d1);

        // ---- Phase D: L4 vs zero-padded W4 column; lanes q==0 hold z[m]
        {
            f32x4 z = {b4v, b4v, b4v, b4v};
            z = __builtin_amdgcn_mfma_f32_16x16x32_f16(wf4, h3, z, 0, 0, 0);
            if (q == 0) {                        // younger op #2
                const int e0 = (g << 4) + m;
                if (e0 < E) out[e0] = 1.0f / (1.0f + __expf(-z[0]));
            }
        }
        // label pass-through                    // younger op #3
        const int eL = (g << 4) + lane;
        if (lane < 16 && eL < E) out[E + eL] = (float)ed_cur.w;

        if (last) break;
        g = gn; gn = gf; ed_cur = ed_nxt; ed_nxt = ed_fut;
    }
}

extern "C" void kernel_launch(void* const* d_in, const int* in_sizes, int n_in,
                              void* d_out, int out_size, void* d_ws, size_t ws_size,
                              hipStream_t stream)
{
    const float* drug  = (const float*)d_in[0];
    // d_in[1] (cell_hidden_out), d_in[3] (proj_W), d_in[4] (proj_b): dead code
    const int*   edges = (const int*)d_in[2];
    const float* W1 = (const float*)d_in[5];
    const float* b1 = (const float*)d_in[6];
    const float* W2 = (const float*)d_in[7];
    const float* b2 = (const float*)d_in[8];
    const float* W3 = (const float*)d_in[9];
    const float* b3 = (const float*)d_in[10];
    const float* W4 = (const float*)d_in[11];
    const float* b4 = (const float*)d_in[12];
    float* out = (float*)d_out;
    f16*   tab = (f16*)d_ws;   // [0,1MB): f16 table; [1MB,+13KB): weight blob

    const int E  = in_sizes[2] / 4;
    const int NG = (E + 15) / 16;

    hipLaunchKernelGGL(synergy_prepass, dim3(513), dim3(256), 0, stream,
                       drug, W1, W2, W3, W4, tab);
    int blocks = (NG + 3) / 4;
    if (blocks > 768) blocks = 768;          // 3 blocks/CU x 256 CUs
    hipLaunchKernelGGL(synergy_main, dim3(blocks), dim3(256), 0, stream,
                       tab, edges, b1, b2, b3, b4, out, E, NG);
}